// Round 1
// baseline (648.449 us; speedup 1.0000x reference)
//
#include <hip/hip_runtime.h>
#include <math.h>

// InfoNCE loss: a,p,n are [B, D] f32. Per row:
//   pos = dot(a,p)/(max(|a|,eps)*max(|p|,eps))
//   neg = dot(a,n)/(max(|a|,eps)*max(|n|,eps))
//   loss_i = logsumexp(pos/T, neg/T) - pos/T
// out = mean(loss_i)

#define D_DIM 512
#define TEMP_INV (1.0f / 1.5f)
#define EPS_N 1e-12f

constexpr int BLOCKS = 2048;
constexpr int TPB = 256;
constexpr int WAVES_PER_BLOCK = TPB / 64;               // 4
constexpr int TOTAL_WAVES = BLOCKS * WAVES_PER_BLOCK;   // 8192

__global__ __launch_bounds__(TPB) void infonce_partial(
    const float* __restrict__ a, const float* __restrict__ p,
    const float* __restrict__ n, float* __restrict__ partial, int B) {
  const int lane = threadIdx.x & 63;
  const int wave_in_block = threadIdx.x >> 6;
  const int wave = blockIdx.x * WAVES_PER_BLOCK + wave_in_block;

  float loss_acc = 0.0f;

  for (int row = wave; row < B; row += TOTAL_WAVES) {
    const float4* a4 = (const float4*)(a + (size_t)row * D_DIM);
    const float4* p4 = (const float4*)(p + (size_t)row * D_DIM);
    const float4* n4 = (const float4*)(n + (size_t)row * D_DIM);

    float aa = 0.f, pp = 0.f, nn = 0.f, ap = 0.f, an = 0.f;
#pragma unroll
    for (int j = 0; j < 2; ++j) {
      const int idx = lane + 64 * j;       // 0..127 float4s cover 512 floats
      float4 av = a4[idx];
      float4 pv = p4[idx];
      float4 nv = n4[idx];
      aa = fmaf(av.x, av.x, fmaf(av.y, av.y, fmaf(av.z, av.z, fmaf(av.w, av.w, aa))));
      pp = fmaf(pv.x, pv.x, fmaf(pv.y, pv.y, fmaf(pv.z, pv.z, fmaf(pv.w, pv.w, pp))));
      nn = fmaf(nv.x, nv.x, fmaf(nv.y, nv.y, fmaf(nv.z, nv.z, fmaf(nv.w, nv.w, nn))));
      ap = fmaf(av.x, pv.x, fmaf(av.y, pv.y, fmaf(av.z, pv.z, fmaf(av.w, pv.w, ap))));
      an = fmaf(av.x, nv.x, fmaf(av.y, nv.y, fmaf(av.z, nv.z, fmaf(av.w, nv.w, an))));
    }

    // Butterfly reduce all 5 partials across the 64-lane wave.
#pragma unroll
    for (int off = 32; off > 0; off >>= 1) {
      aa += __shfl_xor(aa, off);
      pp += __shfl_xor(pp, off);
      nn += __shfl_xor(nn, off);
      ap += __shfl_xor(ap, off);
      an += __shfl_xor(an, off);
    }

    const float na = fmaxf(sqrtf(aa), EPS_N);
    const float np = fmaxf(sqrtf(pp), EPS_N);
    const float nv = fmaxf(sqrtf(nn), EPS_N);
    const float pos = ap / (na * np);
    const float neg = an / (na * nv);
    const float l0 = pos * TEMP_INV;
    const float l1 = neg * TEMP_INV;
    const float m = fmaxf(l0, l1);
    const float lse = m + logf(expf(l0 - m) + expf(l1 - m));
    loss_acc += (lse - l0);   // identical value on all 64 lanes
  }

  __shared__ float sh[WAVES_PER_BLOCK];
  if (lane == 0) sh[wave_in_block] = loss_acc;
  __syncthreads();
  if (threadIdx.x == 0) {
    float s = 0.f;
#pragma unroll
    for (int i = 0; i < WAVES_PER_BLOCK; ++i) s += sh[i];
    partial[blockIdx.x] = s;
  }
}

__global__ __launch_bounds__(256) void reduce_partials(
    const float* __restrict__ partial, float* __restrict__ out, int B) {
  __shared__ float sh[256];
  float s = 0.f;
  for (int i = threadIdx.x; i < BLOCKS; i += 256) s += partial[i];
  sh[threadIdx.x] = s;
  __syncthreads();
  for (int off = 128; off > 0; off >>= 1) {
    if (threadIdx.x < off) sh[threadIdx.x] += sh[threadIdx.x + off];
    __syncthreads();
  }
  if (threadIdx.x == 0) out[0] = sh[0] / (float)B;
}

extern "C" void kernel_launch(void* const* d_in, const int* in_sizes, int n_in,
                              void* d_out, int out_size, void* d_ws, size_t ws_size,
                              hipStream_t stream) {
  const float* a = (const float*)d_in[0];   // anchors
  const float* p = (const float*)d_in[1];   // positives
  const float* n = (const float*)d_in[2];   // negatives
  float* partial = (float*)d_ws;            // BLOCKS floats = 8 KB
  float* out = (float*)d_out;
  const int B = in_sizes[0] / D_DIM;

  infonce_partial<<<BLOCKS, TPB, 0, stream>>>(a, p, n, partial, B);
  reduce_partials<<<1, 256, 0, stream>>>(partial, out, B);
}